// Round 1
// baseline (566.184 us; speedup 1.0000x reference)
//
#include <hip/hip_runtime.h>

#define HD 512
#define B_MOL 64
#define ASV 24
#define ASU 32
#define AF 133
#define BFD 147
#define NA_SV (B_MOL*ASV)     // 1536
#define NB_SV (2*B_MOL*ASV)   // 3072
#define NA_SU (B_MOL*ASU)     // 2048
#define NB_SU (2*B_MOL*ASU)   // 4096
#define NPAIR (B_MOL*ASV*ASU) // 49152

// ---------------- tiled f32 GEMM: out = op((ADD_C?Cin:0) + A@W + bias) ------
// BM=BN=64, BK=16, 256 threads, 4x4 per thread.
template<bool ADD_C, bool BIAS, bool RELU, bool STORE_RELU2>
__launch_bounds__(256)
__global__ void gemm_k(const float* __restrict__ A, const float* __restrict__ W,
                       const float* __restrict__ Cin, const float* __restrict__ bias,
                       float* __restrict__ out, float* __restrict__ out2,
                       int M, int N, int K) {
  __shared__ float As[16][64];  // As[k][m]
  __shared__ float Ws[16][64];  // Ws[k][n]
  const int bm = blockIdx.y * 64;
  const int bn = blockIdx.x * 64;
  const int tid = threadIdx.x;
  const int tr = (tid >> 4) << 2;   // 0..60
  const int tc = (tid & 15) << 2;   // 0..60
  const int ar = tid >> 2;          // 0..63
  const int ak = (tid & 3) << 2;    // 0,4,8,12
  const int wr = tid >> 4;          // 0..15
  const int wc = (tid & 15) << 2;   // 0..60
  float acc[4][4] = {};
  const bool a_vec = ((K & 3) == 0);

  for (int k0 = 0; k0 < K; k0 += 16) {
    // stage A tile (transposed into As[k][m])
    if (a_vec && (k0 + 16 <= K)) {
      const float4 av = *reinterpret_cast<const float4*>(A + (size_t)(bm + ar) * K + k0 + ak);
      As[ak + 0][ar] = av.x; As[ak + 1][ar] = av.y;
      As[ak + 2][ar] = av.z; As[ak + 3][ar] = av.w;
    } else {
#pragma unroll
      for (int e = 0; e < 4; ++e) {
        const int k = k0 + ak + e;
        As[ak + e][ar] = (k < K) ? A[(size_t)(bm + ar) * K + k] : 0.f;
      }
    }
    // stage W tile
    if (k0 + wr < K) {
      const float4 wv = *reinterpret_cast<const float4*>(W + (size_t)(k0 + wr) * N + bn + wc);
      *reinterpret_cast<float4*>(&Ws[wr][wc]) = wv;
    } else {
      Ws[wr][wc] = 0.f; Ws[wr][wc + 1] = 0.f; Ws[wr][wc + 2] = 0.f; Ws[wr][wc + 3] = 0.f;
    }
    __syncthreads();
#pragma unroll
    for (int kk = 0; kk < 16; ++kk) {
      const float4 a4 = *reinterpret_cast<const float4*>(&As[kk][tr]);
      const float4 w4 = *reinterpret_cast<const float4*>(&Ws[kk][tc]);
      const float af_[4] = {a4.x, a4.y, a4.z, a4.w};
      const float wf_[4] = {w4.x, w4.y, w4.z, w4.w};
#pragma unroll
      for (int r = 0; r < 4; ++r)
#pragma unroll
        for (int c = 0; c < 4; ++c)
          acc[r][c] = fmaf(af_[r], wf_[c], acc[r][c]);
    }
    __syncthreads();
  }

#pragma unroll
  for (int r = 0; r < 4; ++r) {
    const size_t idx = (size_t)(bm + tr + r) * N + bn + tc;
    float4 v = make_float4(acc[r][0], acc[r][1], acc[r][2], acc[r][3]);
    if (ADD_C) {
      const float4 c = *reinterpret_cast<const float4*>(Cin + idx);
      v.x += c.x; v.y += c.y; v.z += c.z; v.w += c.w;
    }
    if (BIAS) {
      const float4 bb = *reinterpret_cast<const float4*>(bias + bn + tc);
      v.x += bb.x; v.y += bb.y; v.z += bb.z; v.w += bb.w;
    }
    if (RELU) {
      v.x = fmaxf(v.x, 0.f); v.y = fmaxf(v.y, 0.f);
      v.z = fmaxf(v.z, 0.f); v.w = fmaxf(v.w, 0.f);
    }
    *reinterpret_cast<float4*>(out + idx) = v;
    if (STORE_RELU2) {
      float4 r2 = make_float4(fmaxf(v.x, 0.f), fmaxf(v.y, 0.f), fmaxf(v.z, 0.f), fmaxf(v.w, 0.f));
      *reinterpret_cast<float4*>(out2 + idx) = r2;
    }
  }
}

// ---------------- a_msg[a] = sum_{k<6} msg[a2b[a][k]] ----------------------
__global__ void gather_sum_k(const float* __restrict__ msg, const int* __restrict__ a2b,
                             float* __restrict__ amsg, int NA) {
  const int idx = blockIdx.x * blockDim.x + threadIdx.x;  // NA*128 threads
  const int a = idx >> 7;
  const int h4 = (idx & 127) << 2;
  if (a >= NA) return;
  float4 s = make_float4(0.f, 0.f, 0.f, 0.f);
#pragma unroll
  for (int k = 0; k < 6; ++k) {
    const int b = a2b[a * 6 + k];
    const float4 v = *reinterpret_cast<const float4*>(msg + (size_t)b * HD + h4);
    s.x += v.x; s.y += v.y; s.z += v.z; s.w += v.w;
  }
  *reinterpret_cast<float4*>(amsg + (size_t)a * HD + h4) = s;
}

// ---------------- X[b] = amsg[b2a[b]] - msg[b2revb[b]] ---------------------
__global__ void gather_diff_k(const float* __restrict__ amsg, const float* __restrict__ msg,
                              const int* __restrict__ b2a, const int* __restrict__ b2revb,
                              float* __restrict__ X, int NB) {
  const int idx = blockIdx.x * blockDim.x + threadIdx.x;  // NB*128 threads
  const int b = idx >> 7;
  const int h4 = (idx & 127) << 2;
  if (b >= NB) return;
  const int a = b2a[b];
  const int rb = b2revb[b];
  const float4 u = *reinterpret_cast<const float4*>(amsg + (size_t)a * HD + h4);
  const float4 v = *reinterpret_cast<const float4*>(msg + (size_t)rb * HD + h4);
  *reinterpret_cast<float4*>(X + (size_t)b * HD + h4) =
      make_float4(u.x - v.x, u.y - v.y, u.z - v.z, u.w - v.w);
}

// ---------------- mol mean over atoms -> out[b*2048 + off + c] -------------
__global__ void mol_mean_k(const float* __restrict__ atom_h, float* __restrict__ out,
                           int natoms, int out_off) {
  const int b = blockIdx.x;
  const float inv = 1.0f / (float)natoms;
  for (int c = threadIdx.x; c < HD; c += blockDim.x) {
    float s = 0.f;
    for (int a = 0; a < natoms; ++a)
      s += atom_h[((size_t)b * natoms + a) * HD + c];
    out[(size_t)b * 2048 + out_off + c] = s * inv;
  }
}

// ---------------- score[p] = relu(U[svrow]+V[surow]) . w_a2 + b_a2 ---------
__global__ void score_k(const float* __restrict__ U, const float* __restrict__ V,
                        const float* __restrict__ w_a2, const float* __restrict__ b_a2,
                        float* __restrict__ scores) {
  const int gw = (blockIdx.x * blockDim.x + threadIdx.x) >> 6;  // pair id
  const int lane = threadIdx.x & 63;
  if (gw >= NPAIR) return;
  const int b = gw / (ASV * ASU);
  const int r = gw % (ASV * ASU);
  const int i = r >> 5;   // /ASU
  const int j = r & 31;   // %ASU
  const float* u = U + (size_t)(b * ASV + i) * 1024;
  const float* v = V + (size_t)(b * ASU + j) * 1024;
  float s = 0.f;
#pragma unroll
  for (int t = 0; t < 16; ++t) {
    const int h = lane + (t << 6);
    const float x = fmaxf(u[h] + v[h], 0.f);
    s = fmaf(x, w_a2[h], s);
  }
#pragma unroll
  for (int off = 32; off; off >>= 1) s += __shfl_xor(s, off);
  if (lane == 0) scores[gw] = s + b_a2[0];
}

// ---------------- global softmax stats: stat = {max, 1/sum} ----------------
__global__ void softmax_reduce_k(const float* __restrict__ scores, float* __restrict__ stat) {
  __shared__ float red[256];
  const int tid = threadIdx.x;
  float m = -1e30f;
  for (int p = tid; p < NPAIR; p += 256) m = fmaxf(m, scores[p]);
  red[tid] = m; __syncthreads();
  for (int s = 128; s; s >>= 1) {
    if (tid < s) red[tid] = fmaxf(red[tid], red[tid + s]);
    __syncthreads();
  }
  const float gmax = red[0];
  __syncthreads();
  float sum = 0.f;
  for (int p = tid; p < NPAIR; p += 256) sum += expf(scores[p] - gmax);
  red[tid] = sum; __syncthreads();
  for (int s = 128; s; s >>= 1) {
    if (tid < s) red[tid] += red[tid + s];
    __syncthreads();
  }
  if (tid == 0) { stat[0] = gmax; stat[1] = 1.0f / red[0]; }
}

// ---------------- per-molecule attention row/col sums + weighted means -----
__global__ void mol_combs_k(const float* __restrict__ scores, const float* __restrict__ stat,
                            const float* __restrict__ ah_sv, const float* __restrict__ ah_su,
                            float* __restrict__ out) {
  __shared__ float attRow[ASV];
  __shared__ float attCol[ASU];
  const int b = blockIdx.x;
  const int tid = threadIdx.x;
  if (tid < ASV) attRow[tid] = 0.f;
  if (tid < ASU) attCol[tid] = 0.f;
  __syncthreads();
  const float gmax = stat[0], inv = stat[1];
  for (int p = tid; p < ASV * ASU; p += 256) {
    const float w = expf(scores[b * ASV * ASU + p] - gmax) * inv;
    atomicAdd(&attRow[p >> 5], w);
    atomicAdd(&attCol[p & 31], w);
  }
  __syncthreads();
  const float invP = 1.0f / (float)(ASV * ASU);
  for (int c = tid; c < HD; c += 256) {
    float s = 0.f;
    for (int i = 0; i < ASV; ++i)
      s += attRow[i] * ah_sv[((size_t)b * ASV + i) * HD + c];
    out[(size_t)b * 2048 + 512 + c] = s * invP;
  }
  for (int c = tid; c < HD; c += 256) {
    float s = 0.f;
    for (int j = 0; j < ASU; ++j)
      s += attCol[j] * ah_su[((size_t)b * ASU + j) * HD + c];
    out[(size_t)b * 2048 + 1024 + c] = s * invP;
  }
}

extern "C" void kernel_launch(void* const* d_in, const int* in_sizes, int n_in,
                              void* d_out, int out_size, void* d_ws, size_t ws_size,
                              hipStream_t stream) {
  (void)in_sizes; (void)n_in; (void)out_size; (void)ws_size;
  const float* f_atoms_sv = (const float*)d_in[0];
  const float* f_bonds_sv = (const float*)d_in[1];
  const int*   a2b_sv     = (const int*)d_in[2];
  const int*   b2a_sv     = (const int*)d_in[3];
  const int*   b2revb_sv  = (const int*)d_in[4];
  const float* f_atoms_su = (const float*)d_in[5];
  const float* f_bonds_su = (const float*)d_in[6];
  const int*   a2b_su     = (const int*)d_in[7];
  const int*   b2a_su     = (const int*)d_in[8];
  const int*   b2revb_su  = (const int*)d_in[9];
  const float* W_i  = (const float*)d_in[10];
  const float* W_h  = (const float*)d_in[11];
  const float* W_o  = (const float*)d_in[12];
  const float* b_o  = (const float*)d_in[13];
  const float* W_a1 = (const float*)d_in[14];
  const float* b_a1 = (const float*)d_in[15];
  const float* W_a2 = (const float*)d_in[16];
  const float* b_a2 = (const float*)d_in[17];
  float* out = (float*)d_out;

  float* ws = (float*)d_ws;
  float* inp_sv  = ws;                       // 3072*512
  float* msg_sv  = inp_sv  + (size_t)NB_SV * HD;
  float* X_sv    = msg_sv  + (size_t)NB_SV * HD;
  float* amsg_sv = X_sv    + (size_t)NB_SV * HD;   // 1536*512
  float* ah_sv   = amsg_sv + (size_t)NA_SV * HD;
  float* inp_su  = ah_sv   + (size_t)NA_SV * HD;   // 4096*512
  float* msg_su  = inp_su  + (size_t)NB_SU * HD;
  float* X_su    = msg_su  + (size_t)NB_SU * HD;
  float* amsg_su = X_su    + (size_t)NB_SU * HD;   // 2048*512
  float* ah_su   = amsg_su + (size_t)NA_SU * HD;
  float* scores  = ah_su   + (size_t)NA_SU * HD;   // 49152
  float* stat    = scores  + NPAIR;                // 2
  float* U = inp_sv;   // reuse: 1536*1024 == 3072*512
  float* V = inp_su;   // reuse: 2048*1024 == 4096*512

  // ---------------- solvent MPN ----------------
  gemm_k<false,false,false,true><<<dim3(HD/64, NB_SV/64), 256, 0, stream>>>(
      f_bonds_sv, W_i, nullptr, nullptr, inp_sv, msg_sv, NB_SV, HD, BFD);
  for (int d = 0; d < 2; ++d) {
    gather_sum_k<<<NA_SV * 128 / 256, 256, 0, stream>>>(msg_sv, a2b_sv, amsg_sv, NA_SV);
    gather_diff_k<<<NB_SV * 128 / 256, 256, 0, stream>>>(amsg_sv, msg_sv, b2a_sv, b2revb_sv, X_sv, NB_SV);
    gemm_k<true,false,true,false><<<dim3(HD/64, NB_SV/64), 256, 0, stream>>>(
        X_sv, W_h, inp_sv, nullptr, msg_sv, nullptr, NB_SV, HD, HD);
  }
  gather_sum_k<<<NA_SV * 128 / 256, 256, 0, stream>>>(msg_sv, a2b_sv, amsg_sv, NA_SV);
  gemm_k<false,false,false,false><<<dim3(HD/64, NA_SV/64), 256, 0, stream>>>(
      f_atoms_sv, W_o, nullptr, nullptr, ah_sv, nullptr, NA_SV, HD, AF);
  gemm_k<true,true,true,false><<<dim3(HD/64, NA_SV/64), 256, 0, stream>>>(
      amsg_sv, W_o + (size_t)AF * HD, ah_sv, b_o, ah_sv, nullptr, NA_SV, HD, HD);
  mol_mean_k<<<B_MOL, 256, 0, stream>>>(ah_sv, out, ASV, 0);

  // ---------------- solute MPN ----------------
  gemm_k<false,false,false,true><<<dim3(HD/64, NB_SU/64), 256, 0, stream>>>(
      f_bonds_su, W_i, nullptr, nullptr, inp_su, msg_su, NB_SU, HD, BFD);
  for (int d = 0; d < 2; ++d) {
    gather_sum_k<<<NA_SU * 128 / 256, 256, 0, stream>>>(msg_su, a2b_su, amsg_su, NA_SU);
    gather_diff_k<<<NB_SU * 128 / 256, 256, 0, stream>>>(amsg_su, msg_su, b2a_su, b2revb_su, X_su, NB_SU);
    gemm_k<true,false,true,false><<<dim3(HD/64, NB_SU/64), 256, 0, stream>>>(
        X_su, W_h, inp_su, nullptr, msg_su, nullptr, NB_SU, HD, HD);
  }
  gather_sum_k<<<NA_SU * 128 / 256, 256, 0, stream>>>(msg_su, a2b_su, amsg_su, NA_SU);
  gemm_k<false,false,false,false><<<dim3(HD/64, NA_SU/64), 256, 0, stream>>>(
      f_atoms_su, W_o, nullptr, nullptr, ah_su, nullptr, NA_SU, HD, AF);
  gemm_k<true,true,true,false><<<dim3(HD/64, NA_SU/64), 256, 0, stream>>>(
      amsg_su, W_o + (size_t)AF * HD, ah_su, b_o, ah_su, nullptr, NA_SU, HD, HD);
  mol_mean_k<<<B_MOL, 256, 0, stream>>>(ah_su, out, ASU, 1536);

  // ---------------- factorized pair attention ----------------
  gemm_k<false,true,false,false><<<dim3(1024/64, NA_SV/64), 256, 0, stream>>>(
      ah_sv, W_a1, nullptr, b_a1, U, nullptr, NA_SV, 1024, HD);
  gemm_k<false,false,false,false><<<dim3(1024/64, NA_SU/64), 256, 0, stream>>>(
      ah_su, W_a1 + (size_t)HD * 1024, nullptr, nullptr, V, nullptr, NA_SU, 1024, HD);
  score_k<<<NPAIR / 4, 256, 0, stream>>>(U, V, W_a2, b_a2, scores);
  softmax_reduce_k<<<1, 256, 0, stream>>>(scores, stat);
  mol_combs_k<<<B_MOL, 256, 0, stream>>>(scores, stat, ah_sv, ah_su, out);
}

// Round 2
// 228.614 us; speedup vs baseline: 2.4766x; 2.4766x over previous
//
#include <hip/hip_runtime.h>

#define HD 512
#define B_MOL 64
#define ASV 24
#define ASU 32
#define AF 133
#define BFD 147
#define NA_SV (B_MOL*ASV)     // 1536
#define NB_SV (2*B_MOL*ASV)   // 3072
#define NA_SU (B_MOL*ASU)     // 2048
#define NB_SU (2*B_MOL*ASU)   // 4096
#define NPAIR (B_MOL*ASV*ASU) // 49152
#define KPAD 192              // 147/133 padded

typedef __bf16 bf16x8 __attribute__((ext_vector_type(8)));
typedef float f32x4 __attribute__((ext_vector_type(4)));

__device__ __forceinline__ unsigned short f2bf(float f) {
  unsigned u = __builtin_bit_cast(unsigned, f);
  unsigned r = u + 0x7fffu + ((u >> 16) & 1u);
  return (unsigned short)(r >> 16);
}
__device__ __forceinline__ float bf2f(unsigned short h) {
  unsigned u = ((unsigned)h) << 16;
  return __builtin_bit_cast(float, u);
}

// ============ bf16 MFMA GEMM: out = epilogue(A[M][Kp] @ Bt[N][Kp]^T) ========
// BM=128 BN=64 BK=64, 256 threads (4 waves, 2x2), 16x16x32 MFMA.
// LDS XOR-swizzle: slot' = slot ^ (row&7); staged linearly via global_load_lds
// with inverse-swizzled global source (rule 21).
template<bool ADD_C, bool BIAS, bool RELU, bool RELUB, bool ST_F32, bool ST_BF16>
__launch_bounds__(256)
__global__ void mfma_gemm_k(const unsigned short* __restrict__ A,
                            const unsigned short* __restrict__ Bt,
                            const float* __restrict__ Cin, const float* __restrict__ bias,
                            float* __restrict__ outF, unsigned short* __restrict__ outB,
                            int N, int Kp) {
  __shared__ unsigned short As[2][128 * 64];
  __shared__ unsigned short Bs[2][64 * 64];
  const int tid = threadIdx.x;
  const int bm = blockIdx.y * 128;
  const int bn = blockIdx.x * 64;
  const int lane = tid & 63;
  const int wave = tid >> 6;
  const int wm = (wave >> 1) * 64;
  const int wn = (wave & 1) * 32;

  f32x4 acc[4][2];
#pragma unroll
  for (int mf = 0; mf < 4; ++mf)
#pragma unroll
    for (int nf = 0; nf < 2; ++nf)
      acc[mf][nf] = f32x4{0.f, 0.f, 0.f, 0.f};

  auto stage = [&](int buf, int k0) {
#pragma unroll
    for (int i = 0; i < 4; ++i) {             // A: 128x64 = 1024 x 16B
      const int s = i * 256 + tid;
      const int row = s >> 3, sl = s & 7;
      const int gk = (sl ^ (row & 7)) << 3;
      const unsigned short* gp = A + (size_t)(bm + row) * Kp + k0 + gk;
      __builtin_amdgcn_global_load_lds(
          (const __attribute__((address_space(1))) void*)gp,
          (__attribute__((address_space(3))) void*)&As[buf][s * 8], 16, 0, 0);
    }
#pragma unroll
    for (int i = 0; i < 2; ++i) {             // B: 64x64 = 512 x 16B
      const int s = i * 256 + tid;
      const int row = s >> 3, sl = s & 7;
      const int gk = (sl ^ (row & 7)) << 3;
      const unsigned short* gp = Bt + (size_t)(bn + row) * Kp + k0 + gk;
      __builtin_amdgcn_global_load_lds(
          (const __attribute__((address_space(1))) void*)gp,
          (__attribute__((address_space(3))) void*)&Bs[buf][s * 8], 16, 0, 0);
    }
  };

  stage(0, 0);
  __syncthreads();                            // drain prologue vmcnt
  const int nt = Kp >> 6;
  int cur = 0;
  for (int t = 0; t < nt; ++t) {
    if (t + 1 < nt) stage(cur ^ 1, (t + 1) << 6);
    const int lrow = lane & 15, lgrp = lane >> 4;
#pragma unroll
    for (int kk = 0; kk < 2; ++kk) {
      const int slot = kk * 4 + lgrp;
      bf16x8 af[4], bfr[2];
#pragma unroll
      for (int mf = 0; mf < 4; ++mf) {
        const int row = wm + mf * 16 + lrow;
        af[mf] = *reinterpret_cast<const bf16x8*>(&As[cur][row * 64 + ((slot ^ (row & 7)) << 3)]);
      }
#pragma unroll
      for (int nf = 0; nf < 2; ++nf) {
        const int row = wn + nf * 16 + lrow;
        bfr[nf] = *reinterpret_cast<const bf16x8*>(&Bs[cur][row * 64 + ((slot ^ (row & 7)) << 3)]);
      }
#pragma unroll
      for (int mf = 0; mf < 4; ++mf)
#pragma unroll
        for (int nf = 0; nf < 2; ++nf)
          acc[mf][nf] = __builtin_amdgcn_mfma_f32_16x16x32_bf16(af[mf], bfr[nf], acc[mf][nf], 0, 0, 0);
    }
    __syncthreads();                          // drains prefetch vmcnt + read/write fence
    cur ^= 1;
  }

  const int lrow = lane & 15, lgrp = lane >> 4;
#pragma unroll
  for (int mf = 0; mf < 4; ++mf)
#pragma unroll
    for (int nf = 0; nf < 2; ++nf)
#pragma unroll
      for (int i = 0; i < 4; ++i) {
        const int row = bm + wm + mf * 16 + lgrp * 4 + i;
        const int col = bn + wn + nf * 16 + lrow;
        const size_t idx = (size_t)row * N + col;
        float v = acc[mf][nf][i];
        if (ADD_C) v += Cin[idx];
        if (BIAS) v += bias[col];
        if (RELU) v = fmaxf(v, 0.f);
        if (ST_F32) outF[idx] = v;
        if (ST_BF16) outB[idx] = RELUB ? f2bf(fmaxf(v, 0.f)) : f2bf(v);
      }
}

// ============ weight convert: W[K][N] f32 -> Wt[N][Kp] bf16 (zero-pad) ======
__global__ void wconv_k(const float* __restrict__ W, unsigned short* __restrict__ Wt,
                        int K, int N, int Kp) {
  __shared__ float T[64][65];
  const int k0 = blockIdx.x * 64, n0 = blockIdx.y * 64;
  const int tid = threadIdx.x;
  const int r = tid >> 2;
  const int c4 = (tid & 3) * 16;
  const int k = k0 + r;
#pragma unroll
  for (int j = 0; j < 16; ++j)
    T[c4 + j][r] = (k < K) ? W[(size_t)k * N + n0 + c4 + j] : 0.f;
  __syncthreads();
#pragma unroll
  for (int j = 0; j < 16; ++j)
    Wt[(size_t)(n0 + r) * Kp + k0 + c4 + j] = f2bf(T[r][c4 + j]);
}

// ============ activation convert+pad: in[R][K] f32 -> out[R][Kp] bf16 =======
__global__ void actconv_k(const float* __restrict__ in, unsigned short* __restrict__ outp,
                          int R, int K, int Kp) {
  const int id = blockIdx.x * 256 + threadIdx.x;
  if (id >= R * Kp) return;
  const int r = id / Kp, k = id - r * Kp;
  outp[id] = (k < K) ? f2bf(in[(size_t)r * K + k]) : (unsigned short)0;
}

// ============ amsg[a] = sum_{k<6} msg[a2b[a][k]]  (bf16 in/out, f32 acc) ====
__global__ void gather_sum_k(const unsigned short* __restrict__ msg, const int* __restrict__ a2b,
                             unsigned short* __restrict__ amsg, int NA) {
  const int idx = blockIdx.x * 256 + threadIdx.x;   // NA*64 threads
  const int a = idx >> 6, c8 = (idx & 63) << 3;
  if (a >= NA) return;
  float s[8] = {0.f, 0.f, 0.f, 0.f, 0.f, 0.f, 0.f, 0.f};
#pragma unroll
  for (int k = 0; k < 6; ++k) {
    const int b = a2b[a * 6 + k];
    const uint4 v = *reinterpret_cast<const uint4*>(msg + (size_t)b * HD + c8);
    const unsigned short* p = reinterpret_cast<const unsigned short*>(&v);
#pragma unroll
    for (int e = 0; e < 8; ++e) s[e] += bf2f(p[e]);
  }
  unsigned short o[8];
#pragma unroll
  for (int e = 0; e < 8; ++e) o[e] = f2bf(s[e]);
  *reinterpret_cast<uint4*>(amsg + (size_t)a * HD + c8) = *reinterpret_cast<const uint4*>(o);
}

// ============ X[b] = amsg[b2a[b]] - msg[b2revb[b]] ==========================
__global__ void gather_diff_k(const unsigned short* __restrict__ amsg, const unsigned short* __restrict__ msg,
                              const int* __restrict__ b2a, const int* __restrict__ b2revb,
                              unsigned short* __restrict__ X, int NB) {
  const int idx = blockIdx.x * 256 + threadIdx.x;   // NB*64 threads
  const int b = idx >> 6, c8 = (idx & 63) << 3;
  if (b >= NB) return;
  const int a = b2a[b];
  const int rb = b2revb[b];
  const uint4 uu = *reinterpret_cast<const uint4*>(amsg + (size_t)a * HD + c8);
  const uint4 vv = *reinterpret_cast<const uint4*>(msg + (size_t)rb * HD + c8);
  const unsigned short* up = reinterpret_cast<const unsigned short*>(&uu);
  const unsigned short* vp = reinterpret_cast<const unsigned short*>(&vv);
  unsigned short o[8];
#pragma unroll
  for (int e = 0; e < 8; ++e) o[e] = f2bf(bf2f(up[e]) - bf2f(vp[e]));
  *reinterpret_cast<uint4*>(X + (size_t)b * HD + c8) = *reinterpret_cast<const uint4*>(o);
}

// ============ per-molecule mean of atom_h (f32) -> out ======================
__global__ void mol_mean_k(const float* __restrict__ atom_h, float* __restrict__ out,
                           int natoms, int out_off) {
  const int b = blockIdx.x;
  const float inv = 1.0f / (float)natoms;
  for (int c = threadIdx.x; c < HD; c += blockDim.x) {
    float s = 0.f;
    for (int a = 0; a < natoms; ++a)
      s += atom_h[((size_t)b * natoms + a) * HD + c];
    out[(size_t)b * 2048 + out_off + c] = s * inv;
  }
}

// ============ scores (wave/pair, bf16 U,V) + per-block max ==================
__global__ void score_k(const unsigned short* __restrict__ U, const unsigned short* __restrict__ V,
                        const float* __restrict__ w_a2, const float* __restrict__ b_a2,
                        float* __restrict__ scores, float* __restrict__ pmax) {
  __shared__ float sm[4];
  const int p = blockIdx.x * 4 + (threadIdx.x >> 6);
  const int lane = threadIdx.x & 63;
  const int b = p / (ASV * ASU);
  const int r = p - b * (ASV * ASU);
  const int i = r >> 5, j = r & 31;
  const unsigned short* u = U + (size_t)(b * ASV + i) * 1024;
  const unsigned short* v = V + (size_t)(b * ASU + j) * 1024;
  float s = 0.f;
#pragma unroll
  for (int c = 0; c < 2; ++c) {
    const int base = c * 512 + lane * 8;
    const uint4 uu = *reinterpret_cast<const uint4*>(u + base);
    const uint4 vv = *reinterpret_cast<const uint4*>(v + base);
    const float4 w0 = *reinterpret_cast<const float4*>(w_a2 + base);
    const float4 w1 = *reinterpret_cast<const float4*>(w_a2 + base + 4);
    const unsigned short* up = reinterpret_cast<const unsigned short*>(&uu);
    const unsigned short* vp = reinterpret_cast<const unsigned short*>(&vv);
    const float wf[8] = {w0.x, w0.y, w0.z, w0.w, w1.x, w1.y, w1.z, w1.w};
#pragma unroll
    for (int e = 0; e < 8; ++e) {
      const float x = fmaxf(bf2f(up[e]) + bf2f(vp[e]), 0.f);
      s = fmaf(x, wf[e], s);
    }
  }
#pragma unroll
  for (int off = 32; off; off >>= 1) s += __shfl_xor(s, off);
  if (lane == 0) {
    const float sc = s + b_a2[0];
    scores[p] = sc;
    sm[threadIdx.x >> 6] = sc;
  }
  __syncthreads();
  if (threadIdx.x == 0)
    pmax[blockIdx.x] = fmaxf(fmaxf(sm[0], sm[1]), fmaxf(sm[2], sm[3]));
}

// ============ gmax + 64 partial sums ========================================
__global__ void softsum_k(const float* __restrict__ scores, const float* __restrict__ pmax,
                          float* __restrict__ psum, float* __restrict__ stat) {
  __shared__ float red[256];
  const int tid = threadIdx.x, blk = blockIdx.x;   // 64 blocks
  float m = -1e30f;
  for (int idx = tid; idx < NPAIR / 4; idx += 256) m = fmaxf(m, pmax[idx]);
  red[tid] = m; __syncthreads();
  for (int s = 128; s; s >>= 1) {
    if (tid < s) red[tid] = fmaxf(red[tid], red[tid + s]);
    __syncthreads();
  }
  const float gmax = red[0];
  __syncthreads();
  float sum = 0.f;
  for (int q = tid; q < 768; q += 256) sum += expf(scores[blk * 768 + q] - gmax);
  red[tid] = sum; __syncthreads();
  for (int s = 128; s; s >>= 1) {
    if (tid < s) red[tid] += red[tid + s];
    __syncthreads();
  }
  if (tid == 0) { psum[blk] = red[0]; if (blk == 0) stat[0] = gmax; }
}

// ============ per-molecule att row/col sums + weighted means ================
__global__ void mol_combs_k(const float* __restrict__ scores, const float* __restrict__ psum,
                            const float* __restrict__ stat,
                            const float* __restrict__ ah_sv, const float* __restrict__ ah_su,
                            float* __restrict__ out) {
  __shared__ float attRow[ASV];
  __shared__ float attCol[ASU];
  __shared__ float tot_s;
  const int b = blockIdx.x, tid = threadIdx.x;
  if (tid < ASV) attRow[tid] = 0.f;
  if (tid < ASU) attCol[tid] = 0.f;
  if (tid < 64) {
    float x = psum[tid];
#pragma unroll
    for (int off = 32; off; off >>= 1) x += __shfl_xor(x, off);
    if (tid == 0) tot_s = x;
  }
  __syncthreads();
  const float gmax = stat[0];
  const float inv = 1.0f / tot_s;
  for (int p = tid; p < ASV * ASU; p += 256) {
    const float w = expf(scores[b * ASV * ASU + p] - gmax) * inv;
    atomicAdd(&attRow[p >> 5], w);
    atomicAdd(&attCol[p & 31], w);
  }
  __syncthreads();
  const float invP = 1.0f / (float)(ASV * ASU);
  for (int c = tid; c < HD; c += 256) {
    float s = 0.f;
    for (int i = 0; i < ASV; ++i)
      s += attRow[i] * ah_sv[((size_t)b * ASV + i) * HD + c];
    out[(size_t)b * 2048 + 512 + c] = s * invP;
  }
  for (int c = tid; c < HD; c += 256) {
    float s = 0.f;
    for (int j = 0; j < ASU; ++j)
      s += attCol[j] * ah_su[((size_t)b * ASU + j) * HD + c];
    out[(size_t)b * 2048 + 1024 + c] = s * invP;
  }
}

extern "C" void kernel_launch(void* const* d_in, const int* in_sizes, int n_in,
                              void* d_out, int out_size, void* d_ws, size_t ws_size,
                              hipStream_t stream) {
  (void)in_sizes; (void)n_in; (void)out_size; (void)ws_size;
  const float* f_atoms_sv = (const float*)d_in[0];
  const float* f_bonds_sv = (const float*)d_in[1];
  const int*   a2b_sv     = (const int*)d_in[2];
  const int*   b2a_sv     = (const int*)d_in[3];
  const int*   b2revb_sv  = (const int*)d_in[4];
  const float* f_atoms_su = (const float*)d_in[5];
  const float* f_bonds_su = (const float*)d_in[6];
  const int*   a2b_su     = (const int*)d_in[7];
  const int*   b2a_su     = (const int*)d_in[8];
  const int*   b2revb_su  = (const int*)d_in[9];
  const float* W_i  = (const float*)d_in[10];
  const float* W_h  = (const float*)d_in[11];
  const float* W_o  = (const float*)d_in[12];
  const float* b_o  = (const float*)d_in[13];
  const float* W_a1 = (const float*)d_in[14];
  const float* b_a1 = (const float*)d_in[15];
  const float* W_a2 = (const float*)d_in[16];
  const float* b_a2 = (const float*)d_in[17];
  float* out = (float*)d_out;

  // -------- workspace carve: f32 region then bf16(ushort) region ----------
  float* f = (float*)d_ws;
  float* inp_sv = f;                 f += (size_t)NB_SV * HD;   // 1572864
  float* inp_su = f;                 f += (size_t)NB_SU * HD;   // 2097152
  float* ah_sv  = f;                 f += (size_t)NA_SV * HD;
  float* ah_su  = f;                 f += (size_t)NA_SU * HD;
  float* scores = f;                 f += NPAIR;
  float* pmax   = f;                 f += NPAIR / 4;
  float* psum   = f;                 f += 64;
  float* stat   = f;                 f += 64;

  unsigned short* u = (unsigned short*)f;
  unsigned short* fb_sv_p = u;       u += (size_t)NB_SV * KPAD;
  unsigned short* fb_su_p = u;       u += (size_t)NB_SU * KPAD;
  unsigned short* fa_sv_p = u;       u += (size_t)NA_SV * KPAD;
  unsigned short* fa_su_p = u;       u += (size_t)NA_SU * KPAD;
  unsigned short* Wt_i    = u;       u += (size_t)HD * KPAD;
  unsigned short* Wt_h    = u;       u += (size_t)HD * HD;
  unsigned short* Wt_oa   = u;       u += (size_t)HD * KPAD;
  unsigned short* Wt_oh   = u;       u += (size_t)HD * HD;
  unsigned short* Wt_a1sv = u;       u += (size_t)1024 * HD;
  unsigned short* Wt_a1su = u;       u += (size_t)1024 * HD;
  unsigned short* msg_sv  = u;       u += (size_t)NB_SV * HD;
  unsigned short* msg_su  = u;       u += (size_t)NB_SU * HD;
  unsigned short* X_sv    = u;       u += (size_t)NB_SV * HD;
  unsigned short* X_su    = u;       u += (size_t)NB_SU * HD;
  unsigned short* amsg_sv = u;       u += (size_t)NA_SV * HD;
  unsigned short* amsg_su = u;       u += (size_t)NA_SU * HD;
  unsigned short* ahb_sv  = u;       u += (size_t)NA_SV * HD;
  unsigned short* ahb_su  = u;       u += (size_t)NA_SU * HD;
  // aliases (lifetimes disjoint):
  float* tmpo_sv = (float*)X_sv;            // X dead after depth loop
  float* tmpo_su = (float*)X_su;
  unsigned short* U_b = (unsigned short*)inp_sv;  // inp dead after depth loop
  unsigned short* V_b = (unsigned short*)inp_su;

  // -------- weight + activation conversion --------
  wconv_k<<<dim3(KPAD/64, HD/64), 256, 0, stream>>>(W_i, Wt_i, BFD, HD, KPAD);
  wconv_k<<<dim3(HD/64, HD/64), 256, 0, stream>>>(W_h, Wt_h, HD, HD, HD);
  wconv_k<<<dim3(KPAD/64, HD/64), 256, 0, stream>>>(W_o, Wt_oa, AF, HD, KPAD);
  wconv_k<<<dim3(HD/64, HD/64), 256, 0, stream>>>(W_o + (size_t)AF * HD, Wt_oh, HD, HD, HD);
  wconv_k<<<dim3(HD/64, 1024/64), 256, 0, stream>>>(W_a1, Wt_a1sv, HD, 1024, HD);
  wconv_k<<<dim3(HD/64, 1024/64), 256, 0, stream>>>(W_a1 + (size_t)HD * 1024, Wt_a1su, HD, 1024, HD);
  actconv_k<<<(NB_SV*KPAD + 255)/256, 256, 0, stream>>>(f_bonds_sv, fb_sv_p, NB_SV, BFD, KPAD);
  actconv_k<<<(NB_SU*KPAD + 255)/256, 256, 0, stream>>>(f_bonds_su, fb_su_p, NB_SU, BFD, KPAD);
  actconv_k<<<(NA_SV*KPAD + 255)/256, 256, 0, stream>>>(f_atoms_sv, fa_sv_p, NA_SV, AF, KPAD);
  actconv_k<<<(NA_SU*KPAD + 255)/256, 256, 0, stream>>>(f_atoms_su, fa_su_p, NA_SU, AF, KPAD);

  // -------- solvent MPN --------
  mfma_gemm_k<false,false,false,true,true,true><<<dim3(HD/64, NB_SV/128), 256, 0, stream>>>(
      fb_sv_p, Wt_i, nullptr, nullptr, inp_sv, msg_sv, HD, KPAD);
  for (int d = 0; d < 2; ++d) {
    gather_sum_k<<<NA_SV*64/256, 256, 0, stream>>>(msg_sv, a2b_sv, amsg_sv, NA_SV);
    gather_diff_k<<<NB_SV*64/256, 256, 0, stream>>>(amsg_sv, msg_sv, b2a_sv, b2revb_sv, X_sv, NB_SV);
    mfma_gemm_k<true,false,true,false,false,true><<<dim3(HD/64, NB_SV/128), 256, 0, stream>>>(
        X_sv, Wt_h, inp_sv, nullptr, nullptr, msg_sv, HD, HD);
  }
  gather_sum_k<<<NA_SV*64/256, 256, 0, stream>>>(msg_sv, a2b_sv, amsg_sv, NA_SV);
  mfma_gemm_k<false,false,false,false,true,false><<<dim3(HD/64, NA_SV/128), 256, 0, stream>>>(
      fa_sv_p, Wt_oa, nullptr, nullptr, tmpo_sv, nullptr, HD, KPAD);
  mfma_gemm_k<true,true,true,false,true,true><<<dim3(HD/64, NA_SV/128), 256, 0, stream>>>(
      amsg_sv, Wt_oh, tmpo_sv, b_o, ah_sv, ahb_sv, HD, HD);
  mol_mean_k<<<B_MOL, 256, 0, stream>>>(ah_sv, out, ASV, 0);

  // -------- solute MPN --------
  mfma_gemm_k<false,false,false,true,true,true><<<dim3(HD/64, NB_SU/128), 256, 0, stream>>>(
      fb_su_p, Wt_i, nullptr, nullptr, inp_su, msg_su, HD, KPAD);
  for (int d = 0; d < 2; ++d) {
    gather_sum_k<<<NA_SU*64/256, 256, 0, stream>>>(msg_su, a2b_su, amsg_su, NA_SU);
    gather_diff_k<<<NB_SU*64/256, 256, 0, stream>>>(amsg_su, msg_su, b2a_su, b2revb_su, X_su, NB_SU);
    mfma_gemm_k<true,false,true,false,false,true><<<dim3(HD/64, NB_SU/128), 256, 0, stream>>>(
        X_su, Wt_h, inp_su, nullptr, nullptr, msg_su, HD, HD);
  }
  gather_sum_k<<<NA_SU*64/256, 256, 0, stream>>>(msg_su, a2b_su, amsg_su, NA_SU);
  mfma_gemm_k<false,false,false,false,true,false><<<dim3(HD/64, NA_SU/128), 256, 0, stream>>>(
      fa_su_p, Wt_oa, nullptr, nullptr, tmpo_su, nullptr, HD, KPAD);
  mfma_gemm_k<true,true,true,false,true,true><<<dim3(HD/64, NA_SU/128), 256, 0, stream>>>(
      amsg_su, Wt_oh, tmpo_su, b_o, ah_su, ahb_su, HD, HD);
  mol_mean_k<<<B_MOL, 256, 0, stream>>>(ah_su, out, ASU, 1536);

  // -------- factorized pair attention --------
  mfma_gemm_k<false,true,false,false,false,true><<<dim3(1024/64, NA_SV/128), 256, 0, stream>>>(
      ahb_sv, Wt_a1sv, nullptr, b_a1, nullptr, U_b, 1024, HD);
  mfma_gemm_k<false,false,false,false,false,true><<<dim3(1024/64, NA_SU/128), 256, 0, stream>>>(
      ahb_su, Wt_a1su, nullptr, nullptr, nullptr, V_b, 1024, HD);
  score_k<<<NPAIR/4, 256, 0, stream>>>(U_b, V_b, W_a2, b_a2, scores, pmax);
  softsum_k<<<64, 256, 0, stream>>>(scores, pmax, psum, stat);
  mol_combs_k<<<B_MOL, 256, 0, stream>>>(scores, psum, stat, ah_sv, ah_su, out);
}

// Round 3
// 150.429 us; speedup vs baseline: 3.7638x; 1.5197x over previous
//
#include <hip/hip_runtime.h>

#define HD 512
#define B_MOL 64
#define ASV 24
#define ASU 32
#define AF 133
#define BFD 147
#define NA_SV (B_MOL*ASV)     // 1536
#define NB_SV (2*B_MOL*ASV)   // 3072
#define NA_SU (B_MOL*ASU)     // 2048
#define NB_SU (2*B_MOL*ASU)   // 4096
#define NBT (NB_SV+NB_SU)     // 7168
#define NAT (NA_SV+NA_SU)     // 3584
#define NPAIR (B_MOL*ASV*ASU) // 49152
#define KPAD 192              // 147/133 padded
#define AKP 704               // 192 + 512 combined W_o K

typedef __bf16 bf16x8 __attribute__((ext_vector_type(8)));
typedef float f32x4 __attribute__((ext_vector_type(4)));

__device__ __forceinline__ unsigned short f2bf(float f) {
  unsigned u = __builtin_bit_cast(unsigned, f);
  unsigned r = u + 0x7fffu + ((u >> 16) & 1u);
  return (unsigned short)(r >> 16);
}
__device__ __forceinline__ float bf2f(unsigned short h) {
  unsigned u = ((unsigned)h) << 16;
  return __builtin_bit_cast(float, u);
}

// ============ bf16 MFMA GEMM core: out = epi(A[M][Kp] @ Bt[N][Kp]^T) ========
// BM=128 BN=64 BK=64, 256 threads (4 waves 2x2), 16x16x32 MFMA, dbuf LDS,
// XOR-swizzled LDS via inverse-swizzled global source (rule 21).
template<bool ADD_C, bool BIAS, bool RELU, bool RELUB, bool ST_F32, bool ST_BF16>
__device__ __forceinline__ void gemm_core(const unsigned short* __restrict__ A,
                                          const unsigned short* __restrict__ Bt,
                                          const float* __restrict__ Cin,
                                          const float* __restrict__ bias,
                                          float* __restrict__ outF,
                                          unsigned short* __restrict__ outB,
                                          int N, int Kp, int bm, int bn) {
  __shared__ unsigned short As[2][128 * 64];
  __shared__ unsigned short Bs[2][64 * 64];
  const int tid = threadIdx.x;
  const int lane = tid & 63;
  const int wave = tid >> 6;
  const int wm = (wave >> 1) * 64;
  const int wn = (wave & 1) * 32;

  f32x4 acc[4][2];
#pragma unroll
  for (int mf = 0; mf < 4; ++mf)
#pragma unroll
    for (int nf = 0; nf < 2; ++nf)
      acc[mf][nf] = f32x4{0.f, 0.f, 0.f, 0.f};

  auto stage = [&](int buf, int k0) {
#pragma unroll
    for (int i = 0; i < 4; ++i) {             // A: 128x64 = 1024 x 16B
      const int s = i * 256 + tid;
      const int row = s >> 3, sl = s & 7;
      const int gk = (sl ^ (row & 7)) << 3;
      const unsigned short* gp = A + (size_t)(bm + row) * Kp + k0 + gk;
      __builtin_amdgcn_global_load_lds(
          (const __attribute__((address_space(1))) void*)gp,
          (__attribute__((address_space(3))) void*)&As[buf][s * 8], 16, 0, 0);
    }
#pragma unroll
    for (int i = 0; i < 2; ++i) {             // B: 64x64 = 512 x 16B
      const int s = i * 256 + tid;
      const int row = s >> 3, sl = s & 7;
      const int gk = (sl ^ (row & 7)) << 3;
      const unsigned short* gp = Bt + (size_t)(bn + row) * Kp + k0 + gk;
      __builtin_amdgcn_global_load_lds(
          (const __attribute__((address_space(1))) void*)gp,
          (__attribute__((address_space(3))) void*)&Bs[buf][s * 8], 16, 0, 0);
    }
  };

  stage(0, 0);
  __syncthreads();
  const int nt = Kp >> 6;
  int cur = 0;
  for (int t = 0; t < nt; ++t) {
    if (t + 1 < nt) stage(cur ^ 1, (t + 1) << 6);
    const int lrow = lane & 15, lgrp = lane >> 4;
#pragma unroll
    for (int kk = 0; kk < 2; ++kk) {
      const int slot = kk * 4 + lgrp;
      bf16x8 af[4], bfr[2];
#pragma unroll
      for (int mf = 0; mf < 4; ++mf) {
        const int row = wm + mf * 16 + lrow;
        af[mf] = *reinterpret_cast<const bf16x8*>(&As[cur][row * 64 + ((slot ^ (row & 7)) << 3)]);
      }
#pragma unroll
      for (int nf = 0; nf < 2; ++nf) {
        const int row = wn + nf * 16 + lrow;
        bfr[nf] = *reinterpret_cast<const bf16x8*>(&Bs[cur][row * 64 + ((slot ^ (row & 7)) << 3)]);
      }
#pragma unroll
      for (int mf = 0; mf < 4; ++mf)
#pragma unroll
        for (int nf = 0; nf < 2; ++nf)
          acc[mf][nf] = __builtin_amdgcn_mfma_f32_16x16x32_bf16(af[mf], bfr[nf], acc[mf][nf], 0, 0, 0);
    }
    __syncthreads();
    cur ^= 1;
  }

  const int lrow = lane & 15, lgrp = lane >> 4;
#pragma unroll
  for (int mf = 0; mf < 4; ++mf)
#pragma unroll
    for (int nf = 0; nf < 2; ++nf)
#pragma unroll
      for (int i = 0; i < 4; ++i) {
        const int row = bm + wm + mf * 16 + lgrp * 4 + i;
        const int col = bn + wn + nf * 16 + lrow;
        const size_t idx = (size_t)row * N + col;
        float v = acc[mf][nf][i];
        if (ADD_C) v += Cin[idx];
        if (BIAS) { if (bias) v += bias[col]; }
        if (RELU) v = fmaxf(v, 0.f);
        if (ST_F32) outF[idx] = v;
        if (ST_BF16) outB[idx] = RELUB ? f2bf(fmaxf(v, 0.f)) : f2bf(v);
      }
}

template<bool ADD_C, bool BIAS, bool RELU, bool RELUB, bool ST_F32, bool ST_BF16>
__launch_bounds__(256)
__global__ void mfma_gemm_k(const unsigned short* __restrict__ A,
                            const unsigned short* __restrict__ Bt,
                            const float* __restrict__ Cin, const float* __restrict__ bias,
                            float* __restrict__ outF, unsigned short* __restrict__ outB,
                            int N, int Kp) {
  gemm_core<ADD_C, BIAS, RELU, RELUB, ST_F32, ST_BF16>(
      A, Bt, Cin, bias, outF, outB, N, Kp, blockIdx.y * 128, blockIdx.x * 64);
}

// grid.z merged U/V attention GEMMs (z=0: U=ah_sv@Wa1_sv + b_a1; z=1: V)
__launch_bounds__(256)
__global__ void mfma_gemm_uv_k(const unsigned short* __restrict__ ahb,
                               const unsigned short* __restrict__ Wt_sv,
                               const unsigned short* __restrict__ Wt_su,
                               const float* __restrict__ b_a1,
                               unsigned short* __restrict__ U_b,
                               unsigned short* __restrict__ V_b) {
  const int z = blockIdx.z;
  const int M = z ? NA_SU : NA_SV;
  if ((int)blockIdx.y * 128 >= M) return;
  const unsigned short* A = z ? ahb + (size_t)NA_SV * HD : ahb;
  const unsigned short* Bt = z ? Wt_su : Wt_sv;
  const float* bias = z ? nullptr : b_a1;
  unsigned short* outB = z ? V_b : U_b;
  gemm_core<false, true, false, false, false, true>(
      A, Bt, nullptr, bias, nullptr, outB, 1024, HD, blockIdx.y * 128, blockIdx.x * 64);
}

// ============ all weight transposes in one launch (grid.z = job) ============
struct WJobs {
  const float* src[6];
  unsigned short* dst[6];
  int K[6], N[6], stride[6], colOff[6], region[6];
};
__global__ void wconv_all_k(WJobs J) {
  const int j = blockIdx.z;
  const int k0 = blockIdx.x * 64, n0 = blockIdx.y * 64;
  if (k0 >= J.region[j] || n0 >= J.N[j]) return;
  __shared__ float T[64][65];
  const int tid = threadIdx.x;
  const int r = tid >> 2;
  const int c4 = (tid & 3) * 16;
  const int K = J.K[j], N = J.N[j];
  const float* src = J.src[j];
  const int k = k0 + r;
#pragma unroll
  for (int q = 0; q < 16; ++q)
    T[c4 + q][r] = (k < K) ? src[(size_t)k * N + n0 + c4 + q] : 0.f;
  __syncthreads();
  unsigned short* dst = J.dst[j];
  const int stride = J.stride[j], colOff = J.colOff[j];
#pragma unroll
  for (int q = 0; q < 16; ++q)
    dst[(size_t)(n0 + r) * stride + colOff + k0 + c4 + q] = f2bf(T[r][c4 + q]);
}

// ============ all activation pads/converts in one launch (grid.z = job) =====
struct AJobs {
  const float* src[4];
  unsigned short* dst[4];
  int R[4], K[4], stride[4];
};
__global__ void actconv_all_k(AJobs J) {
  const int j = blockIdx.z;
  const int id = blockIdx.x * 256 + threadIdx.x;
  const int total = J.R[j] * KPAD;
  if (id >= total) return;
  const int r = id / KPAD, kk = id - r * KPAD;
  J.dst[j][(size_t)r * J.stride[j] + kk] =
      (kk < J.K[j]) ? f2bf(J.src[j][(size_t)r * J.K[j] + kk]) : (unsigned short)0;
}

// ============ X[b] = sum_k msg[a2b[b2a[b]][k]] - msg[b2revb[b]] (both graphs)
__global__ void gather_x_k(const unsigned short* __restrict__ msg,
                           const int* __restrict__ a2b_sv, const int* __restrict__ b2a_sv,
                           const int* __restrict__ b2revb_sv,
                           const int* __restrict__ a2b_su, const int* __restrict__ b2a_su,
                           const int* __restrict__ b2revb_su,
                           unsigned short* __restrict__ X) {
  const int idx = blockIdx.x * 256 + threadIdx.x;   // NBT*64 threads
  const int b = idx >> 6, c8 = (idx & 63) << 3;
  if (b >= NBT) return;
  const int* a2b;
  int aL, rev, boff;
  if (b < NB_SV) { a2b = a2b_sv; aL = b2a_sv[b]; rev = b2revb_sv[b]; boff = 0; }
  else {
    const int bl = b - NB_SV;
    a2b = a2b_su; aL = b2a_su[bl]; rev = b2revb_su[bl] + NB_SV; boff = NB_SV;
  }
  float s[8] = {0.f, 0.f, 0.f, 0.f, 0.f, 0.f, 0.f, 0.f};
#pragma unroll
  for (int k = 0; k < 6; ++k) {
    const int bb = a2b[aL * 6 + k] + boff;
    const uint4 v = *reinterpret_cast<const uint4*>(msg + (size_t)bb * HD + c8);
    const unsigned short* p = reinterpret_cast<const unsigned short*>(&v);
#pragma unroll
    for (int e = 0; e < 8; ++e) s[e] += bf2f(p[e]);
  }
  const uint4 rv = *reinterpret_cast<const uint4*>(msg + (size_t)rev * HD + c8);
  const unsigned short* rp = reinterpret_cast<const unsigned short*>(&rv);
  unsigned short o[8];
#pragma unroll
  for (int e = 0; e < 8; ++e) o[e] = f2bf(s[e] - bf2f(rp[e]));
  *reinterpret_cast<uint4*>(X + (size_t)b * HD + c8) = *reinterpret_cast<const uint4*>(o);
}

// ============ final amsg -> a_in[:,192:704] (bf16), both graphs =============
__global__ void gather_sum_k(const unsigned short* __restrict__ msg,
                             const int* __restrict__ a2b_sv, const int* __restrict__ a2b_su,
                             unsigned short* __restrict__ a_in) {
  const int idx = blockIdx.x * 256 + threadIdx.x;   // NAT*64 threads
  const int a = idx >> 6, c8 = (idx & 63) << 3;
  if (a >= NAT) return;
  const int* a2b;
  int aL, boff;
  if (a < NA_SV) { a2b = a2b_sv; aL = a; boff = 0; }
  else { a2b = a2b_su; aL = a - NA_SV; boff = NB_SV; }
  float s[8] = {0.f, 0.f, 0.f, 0.f, 0.f, 0.f, 0.f, 0.f};
#pragma unroll
  for (int k = 0; k < 6; ++k) {
    const int bb = a2b[aL * 6 + k] + boff;
    const uint4 v = *reinterpret_cast<const uint4*>(msg + (size_t)bb * HD + c8);
    const unsigned short* p = reinterpret_cast<const unsigned short*>(&v);
#pragma unroll
    for (int e = 0; e < 8; ++e) s[e] += bf2f(p[e]);
  }
  unsigned short o[8];
#pragma unroll
  for (int e = 0; e < 8; ++e) o[e] = f2bf(s[e]);
  *reinterpret_cast<uint4*>(a_in + (size_t)a * AKP + KPAD + c8) = *reinterpret_cast<const uint4*>(o);
}

// ============ per-molecule means (both graphs, 128 blocks) ==================
__global__ void mol_mean_k(const float* __restrict__ ah, float* __restrict__ out) {
  const int blk = blockIdx.x;
  int natoms, row0, outOff, b;
  if (blk < 64) { b = blk; natoms = ASV; row0 = b * ASV; outOff = 0; }
  else { b = blk - 64; natoms = ASU; row0 = NA_SV + b * ASU; outOff = 1536; }
  const float inv = 1.0f / (float)natoms;
  for (int c = threadIdx.x; c < HD; c += blockDim.x) {
    float s = 0.f;
    for (int a = 0; a < natoms; ++a)
      s += ah[((size_t)(row0 + a)) * HD + c];
    out[(size_t)b * 2048 + outOff + c] = s * inv;
  }
}

// ============ scores (wave/pair) + per-block max ============================
__global__ void score_k(const unsigned short* __restrict__ U, const unsigned short* __restrict__ V,
                        const float* __restrict__ w_a2, const float* __restrict__ b_a2,
                        float* __restrict__ scores, float* __restrict__ pmax) {
  __shared__ float sm[4];
  const int p = blockIdx.x * 4 + (threadIdx.x >> 6);
  const int lane = threadIdx.x & 63;
  const int b = p / (ASV * ASU);
  const int r = p - b * (ASV * ASU);
  const int i = r >> 5, j = r & 31;
  const unsigned short* u = U + (size_t)(b * ASV + i) * 1024;
  const unsigned short* v = V + (size_t)(b * ASU + j) * 1024;
  float s = 0.f;
#pragma unroll
  for (int c = 0; c < 2; ++c) {
    const int base = c * 512 + lane * 8;
    const uint4 uu = *reinterpret_cast<const uint4*>(u + base);
    const uint4 vv = *reinterpret_cast<const uint4*>(v + base);
    const float4 w0 = *reinterpret_cast<const float4*>(w_a2 + base);
    const float4 w1 = *reinterpret_cast<const float4*>(w_a2 + base + 4);
    const unsigned short* up = reinterpret_cast<const unsigned short*>(&uu);
    const unsigned short* vp = reinterpret_cast<const unsigned short*>(&vv);
    const float wf[8] = {w0.x, w0.y, w0.z, w0.w, w1.x, w1.y, w1.z, w1.w};
#pragma unroll
    for (int e = 0; e < 8; ++e) {
      const float x = fmaxf(bf2f(up[e]) + bf2f(vp[e]), 0.f);
      s = fmaf(x, wf[e], s);
    }
  }
#pragma unroll
  for (int off = 32; off; off >>= 1) s += __shfl_xor(s, off);
  if (lane == 0) {
    const float sc = s + b_a2[0];
    scores[p] = sc;
    sm[threadIdx.x >> 6] = sc;
  }
  __syncthreads();
  if (threadIdx.x == 0)
    pmax[blockIdx.x] = fmaxf(fmaxf(sm[0], sm[1]), fmaxf(sm[2], sm[3]));
}

// ============ gmax + 64 partial sums ========================================
__global__ void softsum_k(const float* __restrict__ scores, const float* __restrict__ pmax,
                          float* __restrict__ psum, float* __restrict__ stat) {
  __shared__ float red[256];
  const int tid = threadIdx.x, blk = blockIdx.x;   // 64 blocks
  float m = -1e30f;
  for (int idx = tid; idx < NPAIR / 4; idx += 256) m = fmaxf(m, pmax[idx]);
  red[tid] = m; __syncthreads();
  for (int s = 128; s; s >>= 1) {
    if (tid < s) red[tid] = fmaxf(red[tid], red[tid + s]);
    __syncthreads();
  }
  const float gmax = red[0];
  __syncthreads();
  float sum = 0.f;
  for (int q = tid; q < 768; q += 256) sum += expf(scores[blk * 768 + q] - gmax);
  red[tid] = sum; __syncthreads();
  for (int s = 128; s; s >>= 1) {
    if (tid < s) red[tid] += red[tid + s];
    __syncthreads();
  }
  if (tid == 0) { psum[blk] = red[0]; if (blk == 0) stat[0] = gmax; }
}

// ============ per-molecule att row/col sums + weighted means ================
__global__ void mol_combs_k(const float* __restrict__ scores, const float* __restrict__ psum,
                            const float* __restrict__ stat,
                            const float* __restrict__ ah_sv, const float* __restrict__ ah_su,
                            float* __restrict__ out) {
  __shared__ float attRow[ASV];
  __shared__ float attCol[ASU];
  __shared__ float tot_s;
  const int b = blockIdx.x, tid = threadIdx.x;
  if (tid < ASV) attRow[tid] = 0.f;
  if (tid < ASU) attCol[tid] = 0.f;
  if (tid < 64) {
    float x = psum[tid];
#pragma unroll
    for (int off = 32; off; off >>= 1) x += __shfl_xor(x, off);
    if (tid == 0) tot_s = x;
  }
  __syncthreads();
  const float gmax = stat[0];
  const float inv = 1.0f / tot_s;
  for (int p = tid; p < ASV * ASU; p += 256) {
    const float w = expf(scores[b * ASV * ASU + p] - gmax) * inv;
    atomicAdd(&attRow[p >> 5], w);
    atomicAdd(&attCol[p & 31], w);
  }
  __syncthreads();
  const float invP = 1.0f / (float)(ASV * ASU);
  for (int c = tid; c < HD; c += 256) {
    float s = 0.f;
    for (int i = 0; i < ASV; ++i)
      s += attRow[i] * ah_sv[((size_t)b * ASV + i) * HD + c];
    out[(size_t)b * 2048 + 512 + c] = s * invP;
  }
  for (int c = tid; c < HD; c += 256) {
    float s = 0.f;
    for (int j = 0; j < ASU; ++j)
      s += attCol[j] * ah_su[((size_t)b * ASU + j) * HD + c];
    out[(size_t)b * 2048 + 1024 + c] = s * invP;
  }
}

extern "C" void kernel_launch(void* const* d_in, const int* in_sizes, int n_in,
                              void* d_out, int out_size, void* d_ws, size_t ws_size,
                              hipStream_t stream) {
  (void)in_sizes; (void)n_in; (void)out_size; (void)ws_size;
  const float* f_atoms_sv = (const float*)d_in[0];
  const float* f_bonds_sv = (const float*)d_in[1];
  const int*   a2b_sv     = (const int*)d_in[2];
  const int*   b2a_sv     = (const int*)d_in[3];
  const int*   b2revb_sv  = (const int*)d_in[4];
  const float* f_atoms_su = (const float*)d_in[5];
  const float* f_bonds_su = (const float*)d_in[6];
  const int*   a2b_su     = (const int*)d_in[7];
  const int*   b2a_su     = (const int*)d_in[8];
  const int*   b2revb_su  = (const int*)d_in[9];
  const float* W_i  = (const float*)d_in[10];
  const float* W_h  = (const float*)d_in[11];
  const float* W_o  = (const float*)d_in[12];
  const float* b_o  = (const float*)d_in[13];
  const float* W_a1 = (const float*)d_in[14];
  const float* b_a1 = (const float*)d_in[15];
  const float* W_a2 = (const float*)d_in[16];
  const float* b_a2 = (const float*)d_in[17];
  float* out = (float*)d_out;

  // -------- workspace carve --------
  float* f = (float*)d_ws;
  float* inp    = f;  f += (size_t)NBT * HD;   // 3670016
  float* ah     = f;  f += (size_t)NAT * HD;   // 1835008
  float* scores = f;  f += NPAIR;
  float* pmax   = f;  f += NPAIR / 4;
  float* psum   = f;  f += 64;
  float* stat   = f;  f += 64;

  unsigned short* u = (unsigned short*)f;
  unsigned short* bondsb  = u;  u += (size_t)NBT * KPAD;
  unsigned short* a_in    = u;  u += (size_t)NAT * AKP;
  unsigned short* Wt_i    = u;  u += (size_t)HD * KPAD;
  unsigned short* Wt_h    = u;  u += (size_t)HD * HD;
  unsigned short* Wt_o    = u;  u += (size_t)HD * AKP;
  unsigned short* Wt_a1sv = u;  u += (size_t)1024 * HD;
  unsigned short* Wt_a1su = u;  u += (size_t)1024 * HD;
  unsigned short* msg     = u;  u += (size_t)NBT * HD;
  unsigned short* X       = u;  u += (size_t)NBT * HD;
  unsigned short* ahb     = u;  u += (size_t)NAT * HD;
  // aliases (inp dead after depth loop):
  unsigned short* U_b = (unsigned short*)inp;
  unsigned short* V_b = U_b + (size_t)NA_SV * 1024;

  // -------- conversions (2 launches) --------
  WJobs wj;
  wj.src[0] = W_i;  wj.dst[0] = Wt_i;    wj.K[0] = BFD; wj.N[0] = 512;  wj.stride[0] = KPAD; wj.colOff[0] = 0;    wj.region[0] = KPAD;
  wj.src[1] = W_h;  wj.dst[1] = Wt_h;    wj.K[1] = HD;  wj.N[1] = 512;  wj.stride[1] = HD;   wj.colOff[1] = 0;    wj.region[1] = HD;
  wj.src[2] = W_o;  wj.dst[2] = Wt_o;    wj.K[2] = AF;  wj.N[2] = 512;  wj.stride[2] = AKP;  wj.colOff[2] = 0;    wj.region[2] = KPAD;
  wj.src[3] = W_o + (size_t)AF * HD; wj.dst[3] = Wt_o; wj.K[3] = HD; wj.N[3] = 512; wj.stride[3] = AKP; wj.colOff[3] = KPAD; wj.region[3] = HD;
  wj.src[4] = W_a1; wj.dst[4] = Wt_a1sv; wj.K[4] = HD;  wj.N[4] = 1024; wj.stride[4] = HD;   wj.colOff[4] = 0;    wj.region[4] = HD;
  wj.src[5] = W_a1 + (size_t)HD * 1024; wj.dst[5] = Wt_a1su; wj.K[5] = HD; wj.N[5] = 1024; wj.stride[5] = HD; wj.colOff[5] = 0; wj.region[5] = HD;
  wconv_all_k<<<dim3(8, 16, 6), 256, 0, stream>>>(wj);

  AJobs aj;
  aj.src[0] = f_bonds_sv; aj.dst[0] = bondsb;                        aj.R[0] = NB_SV; aj.K[0] = BFD; aj.stride[0] = KPAD;
  aj.src[1] = f_bonds_su; aj.dst[1] = bondsb + (size_t)NB_SV * KPAD; aj.R[1] = NB_SU; aj.K[1] = BFD; aj.stride[1] = KPAD;
  aj.src[2] = f_atoms_sv; aj.dst[2] = a_in;                          aj.R[2] = NA_SV; aj.K[2] = AF;  aj.stride[2] = AKP;
  aj.src[3] = f_atoms_su; aj.dst[3] = a_in + (size_t)NA_SV * AKP;    aj.R[3] = NA_SU; aj.K[3] = AF;  aj.stride[3] = AKP;
  actconv_all_k<<<dim3((NB_SU * KPAD + 255) / 256, 1, 4), 256, 0, stream>>>(aj);

  // -------- merged MPN (both graphs) --------
  mfma_gemm_k<false,false,false,true,true,true><<<dim3(HD/64, NBT/128), 256, 0, stream>>>(
      bondsb, Wt_i, nullptr, nullptr, inp, msg, HD, KPAD);
  for (int d = 0; d < 2; ++d) {
    gather_x_k<<<NBT * 64 / 256, 256, 0, stream>>>(
        msg, a2b_sv, b2a_sv, b2revb_sv, a2b_su, b2a_su, b2revb_su, X);
    mfma_gemm_k<true,false,true,false,false,true><<<dim3(HD/64, NBT/128), 256, 0, stream>>>(
        X, Wt_h, inp, nullptr, nullptr, msg, HD, HD);
  }
  gather_sum_k<<<NAT * 64 / 256, 256, 0, stream>>>(msg, a2b_sv, a2b_su, a_in);
  mfma_gemm_k<false,true,true,false,true,true><<<dim3(HD/64, NAT/128), 256, 0, stream>>>(
      a_in, Wt_o, nullptr, b_o, ah, ahb, HD, AKP);
  mol_mean_k<<<128, 256, 0, stream>>>(ah, out);

  // -------- factorized pair attention --------
  mfma_gemm_uv_k<<<dim3(1024/64, NA_SU/128, 2), 256, 0, stream>>>(
      ahb, Wt_a1sv, Wt_a1su, b_a1, U_b, V_b);
  score_k<<<NPAIR/4, 256, 0, stream>>>(U_b, V_b, W_a2, b_a2, scores, pmax);
  softsum_k<<<64, 256, 0, stream>>>(scores, pmax, psum, stat);
  mol_combs_k<<<64, 256, 0, stream>>>(scores, psum, stat, ah, ah + (size_t)NA_SV * HD, out);
}

// Round 4
// 127.819 us; speedup vs baseline: 4.4296x; 1.1769x over previous
//
#include <hip/hip_runtime.h>

#define HD 512
#define B_MOL 64
#define ASV 24
#define ASU 32
#define AF 133
#define BFD 147
#define NA_SV (B_MOL*ASV)     // 1536
#define NB_SV (2*B_MOL*ASV)   // 3072
#define NA_SU (B_MOL*ASU)     // 2048
#define NB_SU (2*B_MOL*ASU)   // 4096
#define NBT (NB_SV+NB_SU)     // 7168
#define NAT (NA_SV+NA_SU)     // 3584
#define NPAIR (B_MOL*ASV*ASU) // 49152
#define KPAD 192              // 147/133 padded
#define AKP 704               // 192 + 512 combined W_o K

typedef __bf16 bf16x8 __attribute__((ext_vector_type(8)));
typedef float f32x4 __attribute__((ext_vector_type(4)));

__device__ __forceinline__ unsigned short f2bf(float f) {
  unsigned u = __builtin_bit_cast(unsigned, f);
  unsigned r = u + 0x7fffu + ((u >> 16) & 1u);
  return (unsigned short)(r >> 16);
}
__device__ __forceinline__ float bf2f(unsigned short h) {
  unsigned u = ((unsigned)h) << 16;
  return __builtin_bit_cast(float, u);
}

// ============ bf16 MFMA GEMM core: out = epi(A[M][Kp] @ Bt[N][Kp]^T) ========
// BM=128 BN=64 BK=64, 256 threads (4 waves 2x2), 16x16x32 MFMA, dbuf LDS,
// XOR-swizzled LDS via inverse-swizzled global source (rule 21).
// Epilogue: v = acc (+ bf16 Cin) (+ bias) (relu);
//   ST_F32 -> outF = v; ST_B2 -> outB2 = bf16(v); ST_BF16 -> outB = bf16(RELUB?relu(v):v)
template<bool ADD_C, bool BIAS, bool RELU, bool RELUB, bool ST_F32, bool ST_BF16, bool ST_B2>
__device__ __forceinline__ void gemm_core(const unsigned short* __restrict__ A,
                                          const unsigned short* __restrict__ Bt,
                                          const unsigned short* __restrict__ CinB,
                                          const float* __restrict__ bias,
                                          float* __restrict__ outF,
                                          unsigned short* __restrict__ outB,
                                          unsigned short* __restrict__ outB2,
                                          int N, int Kp, int bm, int bn) {
  __shared__ unsigned short As[2][128 * 64];
  __shared__ unsigned short Bs[2][64 * 64];
  const int tid = threadIdx.x;
  const int lane = tid & 63;
  const int wave = tid >> 6;
  const int wm = (wave >> 1) * 64;
  const int wn = (wave & 1) * 32;

  f32x4 acc[4][2];
#pragma unroll
  for (int mf = 0; mf < 4; ++mf)
#pragma unroll
    for (int nf = 0; nf < 2; ++nf)
      acc[mf][nf] = f32x4{0.f, 0.f, 0.f, 0.f};

  auto stage = [&](int buf, int k0) {
#pragma unroll
    for (int i = 0; i < 4; ++i) {             // A: 128x64 = 1024 x 16B
      const int s = i * 256 + tid;
      const int row = s >> 3, sl = s & 7;
      const int gk = (sl ^ (row & 7)) << 3;
      const unsigned short* gp = A + (size_t)(bm + row) * Kp + k0 + gk;
      __builtin_amdgcn_global_load_lds(
          (const __attribute__((address_space(1))) void*)gp,
          (__attribute__((address_space(3))) void*)&As[buf][s * 8], 16, 0, 0);
    }
#pragma unroll
    for (int i = 0; i < 2; ++i) {             // B: 64x64 = 512 x 16B
      const int s = i * 256 + tid;
      const int row = s >> 3, sl = s & 7;
      const int gk = (sl ^ (row & 7)) << 3;
      const unsigned short* gp = Bt + (size_t)(bn + row) * Kp + k0 + gk;
      __builtin_amdgcn_global_load_lds(
          (const __attribute__((address_space(1))) void*)gp,
          (__attribute__((address_space(3))) void*)&Bs[buf][s * 8], 16, 0, 0);
    }
  };

  stage(0, 0);
  __syncthreads();
  const int nt = Kp >> 6;
  int cur = 0;
  for (int t = 0; t < nt; ++t) {
    if (t + 1 < nt) stage(cur ^ 1, (t + 1) << 6);
    const int lrow = lane & 15, lgrp = lane >> 4;
#pragma unroll
    for (int kk = 0; kk < 2; ++kk) {
      const int slot = kk * 4 + lgrp;
      bf16x8 af[4], bfr[2];
#pragma unroll
      for (int mf = 0; mf < 4; ++mf) {
        const int row = wm + mf * 16 + lrow;
        af[mf] = *reinterpret_cast<const bf16x8*>(&As[cur][row * 64 + ((slot ^ (row & 7)) << 3)]);
      }
#pragma unroll
      for (int nf = 0; nf < 2; ++nf) {
        const int row = wn + nf * 16 + lrow;
        bfr[nf] = *reinterpret_cast<const bf16x8*>(&Bs[cur][row * 64 + ((slot ^ (row & 7)) << 3)]);
      }
#pragma unroll
      for (int mf = 0; mf < 4; ++mf)
#pragma unroll
        for (int nf = 0; nf < 2; ++nf)
          acc[mf][nf] = __builtin_amdgcn_mfma_f32_16x16x32_bf16(af[mf], bfr[nf], acc[mf][nf], 0, 0, 0);
    }
    __syncthreads();
    cur ^= 1;
  }

  const int lrow = lane & 15, lgrp = lane >> 4;
#pragma unroll
  for (int mf = 0; mf < 4; ++mf)
#pragma unroll
    for (int nf = 0; nf < 2; ++nf)
#pragma unroll
      for (int i = 0; i < 4; ++i) {
        const int row = bm + wm + mf * 16 + lgrp * 4 + i;
        const int col = bn + wn + nf * 16 + lrow;
        const size_t idx = (size_t)row * N + col;
        float v = acc[mf][nf][i];
        if (ADD_C) v += bf2f(CinB[idx]);
        if (BIAS) { if (bias) v += bias[col]; }
        if (RELU) v = fmaxf(v, 0.f);
        if (ST_F32) outF[idx] = v;
        if (ST_B2) outB2[idx] = f2bf(v);
        if (ST_BF16) outB[idx] = RELUB ? f2bf(fmaxf(v, 0.f)) : f2bf(v);
      }
}

template<bool ADD_C, bool BIAS, bool RELU, bool RELUB, bool ST_F32, bool ST_BF16, bool ST_B2>
__launch_bounds__(256)
__global__ void mfma_gemm_k(const unsigned short* __restrict__ A,
                            const unsigned short* __restrict__ Bt,
                            const unsigned short* __restrict__ CinB,
                            const float* __restrict__ bias,
                            float* __restrict__ outF, unsigned short* __restrict__ outB,
                            unsigned short* __restrict__ outB2,
                            int N, int Kp) {
  gemm_core<ADD_C, BIAS, RELU, RELUB, ST_F32, ST_BF16, ST_B2>(
      A, Bt, CinB, bias, outF, outB, outB2, N, Kp, blockIdx.y * 128, blockIdx.x * 64);
}

// grid.z merged U/V attention GEMMs (z=0: U=ah_sv@Wa1_sv + b_a1; z=1: V)
__launch_bounds__(256)
__global__ void mfma_gemm_uv_k(const unsigned short* __restrict__ ahb,
                               const unsigned short* __restrict__ Wt_sv,
                               const unsigned short* __restrict__ Wt_su,
                               const float* __restrict__ b_a1,
                               unsigned short* __restrict__ U_b,
                               unsigned short* __restrict__ V_b) {
  const int z = blockIdx.z;
  const int M = z ? NA_SU : NA_SV;
  if ((int)blockIdx.y * 128 >= M) return;
  const unsigned short* A = z ? ahb + (size_t)NA_SV * HD : ahb;
  const unsigned short* Bt = z ? Wt_su : Wt_sv;
  const float* bias = z ? nullptr : b_a1;
  unsigned short* outB = z ? V_b : U_b;
  gemm_core<false, true, false, false, false, true, false>(
      A, Bt, nullptr, bias, nullptr, outB, nullptr, 1024, HD, blockIdx.y * 128, blockIdx.x * 64);
}

// ============ unified conversions: weights (type 0) + activations (type 1) ==
struct CJobs {
  const float* src[10];
  unsigned short* dst[10];
  int type[10], K[10], N[10], stride[10], colOff[10], region[10], R[10];
};
__global__ void conv_all_k(CJobs J) {
  __shared__ float T[64][65];
  const int j = blockIdx.z;
  const int tid = threadIdx.x;
  if (J.type[j] == 0) {
    const int ktiles = J.region[j] >> 6;
    const int tiles = ktiles * (J.N[j] >> 6);
    const int bx = blockIdx.x;
    if (bx >= tiles) return;
    const int k0 = (bx % ktiles) * 64, n0 = (bx / ktiles) * 64;
    const int r = tid >> 2;
    const int c4 = (tid & 3) * 16;
    const int K = J.K[j], N = J.N[j];
    const float* src = J.src[j];
    const int k = k0 + r;
#pragma unroll
    for (int q = 0; q < 16; ++q)
      T[c4 + q][r] = (k < K) ? src[(size_t)k * N + n0 + c4 + q] : 0.f;
    __syncthreads();
    unsigned short* dst = J.dst[j];
    const int stride = J.stride[j], colOff = J.colOff[j];
#pragma unroll
    for (int q = 0; q < 16; ++q)
      dst[(size_t)(n0 + r) * stride + colOff + k0 + c4 + q] = f2bf(T[r][c4 + q]);
  } else {
    const int id = blockIdx.x * 256 + tid;
    const int total = J.R[j] * KPAD;
    if (id >= total) return;
    const int r = id / KPAD, kk = id - r * KPAD;
    J.dst[j][(size_t)r * J.stride[j] + kk] =
        (kk < J.K[j]) ? f2bf(J.src[j][(size_t)r * J.K[j] + kk]) : (unsigned short)0;
  }
}

// ============ X[b] = sum_k msg[a2b[b2a[b]][k]] - msg[b2revb[b]] (both graphs)
__global__ void gather_x_k(const unsigned short* __restrict__ msg,
                           const int* __restrict__ a2b_sv, const int* __restrict__ b2a_sv,
                           const int* __restrict__ b2revb_sv,
                           const int* __restrict__ a2b_su, const int* __restrict__ b2a_su,
                           const int* __restrict__ b2revb_su,
                           unsigned short* __restrict__ X) {
  const int idx = blockIdx.x * 256 + threadIdx.x;   // NBT*64 threads
  const int b = idx >> 6, c8 = (idx & 63) << 3;
  if (b >= NBT) return;
  const int* a2b;
  int aL, rev, boff;
  if (b < NB_SV) { a2b = a2b_sv; aL = b2a_sv[b]; rev = b2revb_sv[b]; boff = 0; }
  else {
    const int bl = b - NB_SV;
    a2b = a2b_su; aL = b2a_su[bl]; rev = b2revb_su[bl] + NB_SV; boff = NB_SV;
  }
  float s[8] = {0.f, 0.f, 0.f, 0.f, 0.f, 0.f, 0.f, 0.f};
#pragma unroll
  for (int k = 0; k < 6; ++k) {
    const int bb = a2b[aL * 6 + k] + boff;
    const uint4 v = *reinterpret_cast<const uint4*>(msg + (size_t)bb * HD + c8);
    const unsigned short* p = reinterpret_cast<const unsigned short*>(&v);
#pragma unroll
    for (int e = 0; e < 8; ++e) s[e] += bf2f(p[e]);
  }
  const uint4 rv = *reinterpret_cast<const uint4*>(msg + (size_t)rev * HD + c8);
  const unsigned short* rp = reinterpret_cast<const unsigned short*>(&rv);
  unsigned short o[8];
#pragma unroll
  for (int e = 0; e < 8; ++e) o[e] = f2bf(s[e] - bf2f(rp[e]));
  *reinterpret_cast<uint4*>(X + (size_t)b * HD + c8) = *reinterpret_cast<const uint4*>(o);
}

// ============ final amsg -> a_in[:,192:704] (bf16), both graphs =============
__global__ void gather_sum_k(const unsigned short* __restrict__ msg,
                             const int* __restrict__ a2b_sv, const int* __restrict__ a2b_su,
                             unsigned short* __restrict__ a_in) {
  const int idx = blockIdx.x * 256 + threadIdx.x;   // NAT*64 threads
  const int a = idx >> 6, c8 = (idx & 63) << 3;
  if (a >= NAT) return;
  const int* a2b;
  int aL, boff;
  if (a < NA_SV) { a2b = a2b_sv; aL = a; boff = 0; }
  else { a2b = a2b_su; aL = a - NA_SV; boff = NB_SV; }
  float s[8] = {0.f, 0.f, 0.f, 0.f, 0.f, 0.f, 0.f, 0.f};
#pragma unroll
  for (int k = 0; k < 6; ++k) {
    const int bb = a2b[aL * 6 + k] + boff;
    const uint4 v = *reinterpret_cast<const uint4*>(msg + (size_t)bb * HD + c8);
    const unsigned short* p = reinterpret_cast<const unsigned short*>(&v);
#pragma unroll
    for (int e = 0; e < 8; ++e) s[e] += bf2f(p[e]);
  }
  unsigned short o[8];
#pragma unroll
  for (int e = 0; e < 8; ++e) o[e] = f2bf(s[e]);
  *reinterpret_cast<uint4*>(a_in + (size_t)a * AKP + KPAD + c8) = *reinterpret_cast<const uint4*>(o);
}

// ============ scores: block = (3 U-rows, molecule); V-block in LDS ==========
__launch_bounds__(256)
__global__ void score2_k(const unsigned short* __restrict__ U, const unsigned short* __restrict__ V,
                         const float* __restrict__ w_a2, const float* __restrict__ b_a2,
                         float* __restrict__ scores, float* __restrict__ pmax) {
  __shared__ unsigned short Vs[32 * 1024];   // 64KB
  __shared__ float wred[4];
  const int it = blockIdx.x;                 // 0..7 (3 U-rows each)
  const int b = blockIdx.y;                  // molecule
  const int tid = threadIdx.x;
  const int lane = tid & 63;
  const int wave = tid >> 6;

  // stage V-block (contiguous 64KB) linearly into LDS
  const unsigned short* vbase = V + (size_t)(b * ASU) * 1024;
#pragma unroll
  for (int i = 0; i < 16; ++i) {
    const int c = i * 256 + tid;             // 4096 chunks of 16B
    __builtin_amdgcn_global_load_lds(
        (const __attribute__((address_space(1))) void*)(vbase + c * 8),
        (__attribute__((address_space(3))) void*)&Vs[c * 8], 16, 0, 0);
  }

  // preload 3 U rows (per-lane 16 elems each) + w_a2 frags into regs
  const int i0 = it * 3;
  bf16x8 uf[3][2];
#pragma unroll
  for (int ii = 0; ii < 3; ++ii) {
    const unsigned short* up = U + (size_t)(b * ASV + i0 + ii) * 1024 + lane * 16;
    uf[ii][0] = *reinterpret_cast<const bf16x8*>(up);
    uf[ii][1] = *reinterpret_cast<const bf16x8*>(up + 8);
  }
  float wv[16];
#pragma unroll
  for (int q = 0; q < 4; ++q) {
    const float4 w4 = *reinterpret_cast<const float4*>(w_a2 + lane * 16 + q * 4);
    wv[q * 4] = w4.x; wv[q * 4 + 1] = w4.y; wv[q * 4 + 2] = w4.z; wv[q * 4 + 3] = w4.w;
  }
  const float bias = b_a2[0];
  __syncthreads();

  float m = -1e30f;
#pragma unroll
  for (int ii = 0; ii < 3; ++ii) {
#pragma unroll
    for (int jj = 0; jj < 8; ++jj) {
      const int j = wave * 8 + jj;
      const bf16x8 v0 = *reinterpret_cast<const bf16x8*>(&Vs[j * 1024 + lane * 16]);
      const bf16x8 v1 = *reinterpret_cast<const bf16x8*>(&Vs[j * 1024 + lane * 16 + 8]);
      float s = 0.f;
#pragma unroll
      for (int e = 0; e < 8; ++e) {
        const float x0 = fmaxf((float)uf[ii][0][e] + (float)v0[e], 0.f);
        s = fmaf(x0, wv[e], s);
        const float x1 = fmaxf((float)uf[ii][1][e] + (float)v1[e], 0.f);
        s = fmaf(x1, wv[8 + e], s);
      }
#pragma unroll
      for (int off = 32; off; off >>= 1) s += __shfl_xor(s, off);
      const float sc = s + bias;
      if (lane == 0) scores[(size_t)b * 768 + (i0 + ii) * 32 + j] = sc;
      m = fmaxf(m, sc);
    }
  }
  if (lane == 0) wred[wave] = m;
  __syncthreads();
  if (tid == 0)
    pmax[b * 8 + it] = fmaxf(fmaxf(wred[0], wred[1]), fmaxf(wred[2], wred[3]));
}

// ============ gmax + 64 partial sums ========================================
__global__ void softsum_k(const float* __restrict__ scores, const float* __restrict__ pmax,
                          float* __restrict__ psum, float* __restrict__ stat) {
  __shared__ float red[256];
  const int tid = threadIdx.x, blk = blockIdx.x;   // 64 blocks
  float m = -1e30f;
  for (int idx = tid; idx < 512; idx += 256) m = fmaxf(m, pmax[idx]);
  red[tid] = m; __syncthreads();
  for (int s = 128; s; s >>= 1) {
    if (tid < s) red[tid] = fmaxf(red[tid], red[tid + s]);
    __syncthreads();
  }
  const float gmax = red[0];
  __syncthreads();
  float sum = 0.f;
  for (int q = tid; q < 768; q += 256) sum += expf(scores[blk * 768 + q] - gmax);
  red[tid] = sum; __syncthreads();
  for (int s = 128; s; s >>= 1) {
    if (tid < s) red[tid] += red[tid + s];
    __syncthreads();
  }
  if (tid == 0) { psum[blk] = red[0]; if (blk == 0) stat[0] = gmax; }
}

// ============ per-molecule: att row/col sums, weighted means + plain means ==
__global__ void mol_combs_k(const float* __restrict__ scores, const float* __restrict__ psum,
                            const float* __restrict__ stat,
                            const float* __restrict__ ah_sv, const float* __restrict__ ah_su,
                            float* __restrict__ out) {
  __shared__ float attRow[ASV];
  __shared__ float attCol[ASU];
  __shared__ float tot_s;
  const int b = blockIdx.x, tid = threadIdx.x;
  if (tid < ASV) attRow[tid] = 0.f;
  if (tid < ASU) attCol[tid] = 0.f;
  if (tid < 64) {
    float x = psum[tid];
#pragma unroll
    for (int off = 32; off; off >>= 1) x += __shfl_xor(x, off);
    if (tid == 0) tot_s = x;
  }
  __syncthreads();
  const float gmax = stat[0];
  const float inv = 1.0f / tot_s;
  for (int p = tid; p < ASV * ASU; p += 256) {
    const float w = expf(scores[b * ASV * ASU + p] - gmax) * inv;
    atomicAdd(&attRow[p >> 5], w);
    atomicAdd(&attCol[p & 31], w);
  }
  __syncthreads();
  const float invP = 1.0f / (float)(ASV * ASU);
  for (int c = tid; c < HD; c += 256) {
    float s_att = 0.f, s_pln = 0.f;
    for (int i = 0; i < ASV; ++i) {
      const float v = ah_sv[((size_t)b * ASV + i) * HD + c];
      s_att = fmaf(attRow[i], v, s_att);
      s_pln += v;
    }
    out[(size_t)b * 2048 + c] = s_pln * (1.0f / ASV);
    out[(size_t)b * 2048 + 512 + c] = s_att * invP;
  }
  for (int c = tid; c < HD; c += 256) {
    float s_att = 0.f, s_pln = 0.f;
    for (int j = 0; j < ASU; ++j) {
      const float v = ah_su[((size_t)b * ASU + j) * HD + c];
      s_att = fmaf(attCol[j], v, s_att);
      s_pln += v;
    }
    out[(size_t)b * 2048 + 1024 + c] = s_att * invP;
    out[(size_t)b * 2048 + 1536 + c] = s_pln * (1.0f / ASU);
  }
}

extern "C" void kernel_launch(void* const* d_in, const int* in_sizes, int n_in,
                              void* d_out, int out_size, void* d_ws, size_t ws_size,
                              hipStream_t stream) {
  (void)in_sizes; (void)n_in; (void)out_size; (void)ws_size;
  const float* f_atoms_sv = (const float*)d_in[0];
  const float* f_bonds_sv = (const float*)d_in[1];
  const int*   a2b_sv     = (const int*)d_in[2];
  const int*   b2a_sv     = (const int*)d_in[3];
  const int*   b2revb_sv  = (const int*)d_in[4];
  const float* f_atoms_su = (const float*)d_in[5];
  const float* f_bonds_su = (const float*)d_in[6];
  const int*   a2b_su     = (const int*)d_in[7];
  const int*   b2a_su     = (const int*)d_in[8];
  const int*   b2revb_su  = (const int*)d_in[9];
  const float* W_i  = (const float*)d_in[10];
  const float* W_h  = (const float*)d_in[11];
  const float* W_o  = (const float*)d_in[12];
  const float* b_o  = (const float*)d_in[13];
  const float* W_a1 = (const float*)d_in[14];
  const float* b_a1 = (const float*)d_in[15];
  const float* W_a2 = (const float*)d_in[16];
  const float* b_a2 = (const float*)d_in[17];
  float* out = (float*)d_out;

  // -------- workspace carve --------
  float* f = (float*)d_ws;
  float* ah     = f;  f += (size_t)NAT * HD;   // 1835008
  float* scores = f;  f += NPAIR;
  float* pmax   = f;  f += 512;
  float* psum   = f;  f += 64;
  float* stat   = f;  f += 64;

  unsigned short* u = (unsigned short*)f;
  unsigned short* bondsb  = u;  u += (size_t)NBT * KPAD;
  unsigned short* a_in    = u;  u += (size_t)NAT * AKP;
  unsigned short* Wt_i    = u;  u += (size_t)HD * KPAD;
  unsigned short* Wt_h    = u;  u += (size_t)HD * HD;
  unsigned short* Wt_o    = u;  u += (size_t)HD * AKP;
  unsigned short* Wt_a1sv = u;  u += (size_t)1024 * HD;
  unsigned short* Wt_a1su = u;  u += (size_t)1024 * HD;
  unsigned short* msg     = u;  u += (size_t)NBT * HD;
  unsigned short* X       = u;  u += (size_t)NBT * HD;
  unsigned short* ahb     = u;  u += (size_t)NAT * HD;
  unsigned short* inpB    = u;  u += (size_t)NBT * HD;
  // aliases (inpB dead after depth loop; NBT*HD == NA_SV*1024 + NA_SU*1024):
  unsigned short* U_b = inpB;
  unsigned short* V_b = U_b + (size_t)NA_SV * 1024;

  // -------- all conversions in one launch --------
  CJobs cj;
  // weights (type 0)
  cj.type[0]=0; cj.src[0]=W_i;  cj.dst[0]=Wt_i;    cj.K[0]=BFD; cj.N[0]=512;  cj.stride[0]=KPAD; cj.colOff[0]=0;    cj.region[0]=KPAD; cj.R[0]=0;
  cj.type[1]=0; cj.src[1]=W_h;  cj.dst[1]=Wt_h;    cj.K[1]=HD;  cj.N[1]=512;  cj.stride[1]=HD;   cj.colOff[1]=0;    cj.region[1]=HD;   cj.R[1]=0;
  cj.type[2]=0; cj.src[2]=W_o;  cj.dst[2]=Wt_o;    cj.K[2]=AF;  cj.N[2]=512;  cj.stride[2]=AKP;  cj.colOff[2]=0;    cj.region[2]=KPAD; cj.R[2]=0;
  cj.type[3]=0; cj.src[3]=W_o + (size_t)AF*HD; cj.dst[3]=Wt_o; cj.K[3]=HD; cj.N[3]=512; cj.stride[3]=AKP; cj.colOff[3]=KPAD; cj.region[3]=HD; cj.R[3]=0;
  cj.type[4]=0; cj.src[4]=W_a1; cj.dst[4]=Wt_a1sv; cj.K[4]=HD;  cj.N[4]=1024; cj.stride[4]=HD;   cj.colOff[4]=0;    cj.region[4]=HD;   cj.R[4]=0;
  cj.type[5]=0; cj.src[5]=W_a1 + (size_t)HD*1024; cj.dst[5]=Wt_a1su; cj.K[5]=HD; cj.N[5]=1024; cj.stride[5]=HD; cj.colOff[5]=0; cj.region[5]=HD; cj.R[5]=0;
  // activations (type 1)
  cj.type[6]=1; cj.src[6]=f_bonds_sv; cj.dst[6]=bondsb;                        cj.R[6]=NB_SV; cj.K[6]=BFD; cj.stride[6]=KPAD; cj.N[6]=0; cj.colOff[6]=0; cj.region[6]=0;
  cj.type[7]=1; cj.src[7]=f_bonds_su; cj.dst[7]=bondsb + (size_t)NB_SV*KPAD;   cj.R[7]=NB_SU; cj.K[7]=BFD; cj.stride[7]=KPAD; cj.N[7]=0; cj.colOff[7]=0; cj.region[7]=0;
  cj.type[8]=1; cj.src[8]=f_atoms_sv; cj.dst[8]=a_in;                          cj.R[8]=NA_SV; cj.K[8]=AF;  cj.stride[8]=AKP;  cj.N[8]=0; cj.colOff[8]=0; cj.region[8]=0;
  cj.type[9]=1; cj.src[9]=f_atoms_su; cj.dst[9]=a_in + (size_t)NA_SV*AKP;      cj.R[9]=NA_SU; cj.K[9]=AF;  cj.stride[9]=AKP;  cj.N[9]=0; cj.colOff[9]=0; cj.region[9]=0;
  conv_all_k<<<dim3((NB_SU * KPAD + 255) / 256, 1, 10), 256, 0, stream>>>(cj);

  // -------- merged MPN (both graphs) --------
  // inp (pre-relu, bf16) -> inpB ; msg = relu(inp) bf16
  mfma_gemm_k<false,false,false,true,false,true,true><<<dim3(HD/64, NBT/128), 256, 0, stream>>>(
      bondsb, Wt_i, nullptr, nullptr, nullptr, msg, inpB, HD, KPAD);
  for (int d = 0; d < 2; ++d) {
    gather_x_k<<<NBT * 64 / 256, 256, 0, stream>>>(
        msg, a2b_sv, b2a_sv, b2revb_sv, a2b_su, b2a_su, b2revb_su, X);
    mfma_gemm_k<true,false,true,false,false,true,false><<<dim3(HD/64, NBT/128), 256, 0, stream>>>(
        X, Wt_h, inpB, nullptr, nullptr, msg, nullptr, HD, HD);
  }
  gather_sum_k<<<NAT * 64 / 256, 256, 0, stream>>>(msg, a2b_sv, a2b_su, a_in);
  mfma_gemm_k<false,true,true,false,true,true,false><<<dim3(HD/64, NAT/128), 256, 0, stream>>>(
      a_in, Wt_o, nullptr, b_o, ah, ahb, nullptr, HD, AKP);

  // -------- factorized pair attention --------
  mfma_gemm_uv_k<<<dim3(1024/64, NA_SU/128, 2), 256, 0, stream>>>(
      ahb, Wt_a1sv, Wt_a1su, b_a1, U_b, V_b);
  score2_k<<<dim3(8, 64), 256, 0, stream>>>(U_b, V_b, W_a2, b_a2, scores, pmax);
  softsum_k<<<64, 256, 0, stream>>>(scores, pmax, psum, stat);
  mol_combs_k<<<64, 256, 0, stream>>>(scores, psum, stat, ah, ah + (size_t)NA_SV * HD, out);
}